// Round 3
// baseline (1095.049 us; speedup 1.0000x reference)
//
#include <hip/hip_runtime.h>
#include <string.h>

typedef unsigned short u16;
typedef __bf16 bf16_t;
typedef bf16_t bf16x8 __attribute__((ext_vector_type(8)));
typedef float f32x4 __attribute__((ext_vector_type(4)));
typedef u16 u16x4 __attribute__((ext_vector_type(4)));

#define MODE_PLAIN 0
#define MODE_QP 1
#define MODE_SPLITN 2
#define MODE_ATOMIC 3
#define MODE_BIASF32 4

__device__ __forceinline__ float bf2f(u16 u) {
  unsigned int x = ((unsigned int)u) << 16;
  return __builtin_bit_cast(float, x);
}
__device__ __forceinline__ u16 f2bf(float f) {
  unsigned int x = __builtin_bit_cast(unsigned int, f);
  x += 0x7fffu + ((x >> 16) & 1u);
  return (u16)(x >> 16);
}

__device__ __forceinline__ void gload_lds16(const void* g, void* l) {
  __builtin_amdgcn_global_load_lds(
      (const __attribute__((address_space(1))) void*)g,
      (__attribute__((address_space(3))) void*)l, 16, 0, 0);
}

struct GemmP {
  const u16* A0; const u16* A1;       // bf16 A (z-select) — used if Af0==nullptr
  const float* Af0; const float* Af1; // f32 A (z-select), converted at stage time
  const u16* B;  long bz;             // bf16 B — used if Bf==nullptr
  const float* Bf;                    // f32 B
  int lda, ldb, K, mode;              // K = per-chunk K; lda/ldb in elems of dtype
  int ksl;                            // log2(#K-chunks); blockIdx.z = z*(1<<ksl)+kc
  u16* C; long cz; int ldc;
  u16* C2;                            // P for QP mode
  float* Cf; long cfz;                // ATOMIC dest / BIASF32 dest
  const float* biasf;                 // BIASF32
};

// C[m][n] = sum_k A[m][k] * B[n][k]   (A: [M,K], B: [N,K]; M,N %128==0, K%64==0)
__global__ __launch_bounds__(256) void gemm_nt(GemmP p) {
  __shared__ u16 smem[2 * 128 * 64];   // A tile then B tile, 16B chunks, XOR swizzle
  const int tid = threadIdx.x;
  const int lane = tid & 63, wave = tid >> 6;
  const int z = blockIdx.z >> p.ksl;
  const int kc = blockIdx.z & ((1 << p.ksl) - 1);
  const long tileM = (long)blockIdx.y * 128;
  const long tileN = (long)blockIdx.x * 128;
  u16* ldsA = smem;
  u16* ldsB = smem + 128 * 64;

  const u16* A = (z == 0) ? p.A0 : p.A1;
  const u16* B = p.B + (long)z * p.bz;
  const float* Af = (z == 0) ? p.Af0 : p.Af1;
  const float* Bf = p.Bf;

  // bf16 staging: issue j covers rows [j*32, j*32+32); lane l -> row j*32+wave*8+l/8
  const int srow = wave * 8 + (lane >> 3);
  const int ssc = lane & 7;
  long aoff[4], boff[4];
#pragma unroll
  for (int j = 0; j < 4; ++j) {
    int r = j * 32 + srow;
    int c = ssc ^ (r & 7);               // LDS[r][ssc] holds global chunk c
    aoff[j] = ((tileM + r) * (long)p.lda + c * 8) * 2;
    boff[j] = ((tileN + r) * (long)p.ldb + c * 8) * 2;
  }
  // f32 staging: thread -> (row = i*16 + tid/16, float4-col = tid%16)
  const int frow = tid >> 4, fcol = tid & 15;

  const int r15 = lane & 15, q = lane >> 4;
  const int wm = (wave & 1) * 64, wn = (wave >> 1) * 64;

  f32x4 acc[4][4];
#pragma unroll
  for (int i = 0; i < 4; ++i)
#pragma unroll
    for (int j = 0; j < 4; ++j) { f32x4 zz = {0.f, 0.f, 0.f, 0.f}; acc[i][j] = zz; }

  const int K64 = p.K >> 6;                 // tiles per chunk
  const long kofs = (long)kc * K64;         // chunk tile offset
  for (int kt = 0; kt < K64; ++kt) {
    const long kb = (kofs + kt) * 128;      // bf16 byte offset of this k-tile
    __syncthreads();   // prior tile fully consumed
    if (Af) {
#pragma unroll
      for (int i = 0; i < 8; ++i) {
        int r = i * 16 + frow;
        f32x4 v = *(const f32x4*)(Af + (tileM + r) * (long)p.lda + (kofs + kt) * 64 + fcol * 4);
        int sc = (fcol >> 1) ^ (r & 7);
        u16x4 o; o[0] = f2bf(v[0]); o[1] = f2bf(v[1]); o[2] = f2bf(v[2]); o[3] = f2bf(v[3]);
        *(u16x4*)(ldsA + (r * 8 + sc) * 8 + (fcol & 1) * 4) = o;
      }
    } else {
#pragma unroll
      for (int j = 0; j < 4; ++j)
        gload_lds16((const char*)A + aoff[j] + kb, (char*)ldsA + (j * 256 + wave * 64) * 16);
    }
    if (Bf) {
#pragma unroll
      for (int i = 0; i < 8; ++i) {
        int r = i * 16 + frow;
        f32x4 v = *(const f32x4*)(Bf + (tileN + r) * (long)p.ldb + (kofs + kt) * 64 + fcol * 4);
        int sc = (fcol >> 1) ^ (r & 7);
        u16x4 o; o[0] = f2bf(v[0]); o[1] = f2bf(v[1]); o[2] = f2bf(v[2]); o[3] = f2bf(v[3]);
        *(u16x4*)(ldsB + (r * 8 + sc) * 8 + (fcol & 1) * 4) = o;
      }
    } else {
#pragma unroll
      for (int j = 0; j < 4; ++j)
        gload_lds16((const char*)B + boff[j] + kb, (char*)ldsB + (j * 256 + wave * 64) * 16);
    }
    __syncthreads();   // staging visible (compiler drains vmcnt/lgkmcnt)
#pragma unroll
    for (int ks = 0; ks < 2; ++ks) {
      bf16x8 af[4], bfr[4];
#pragma unroll
      for (int mt = 0; mt < 4; ++mt) {
        int row = wm + mt * 16 + r15;
        int sc = (ks * 4 + q) ^ (r15 & 7);
        af[mt] = *(const bf16x8*)(ldsA + (row * 8 + sc) * 8);
      }
#pragma unroll
      for (int nt = 0; nt < 4; ++nt) {
        int row = wn + nt * 16 + r15;
        int sc = (ks * 4 + q) ^ (r15 & 7);
        bfr[nt] = *(const bf16x8*)(ldsB + (row * 8 + sc) * 8);
      }
#pragma unroll
      for (int mt = 0; mt < 4; ++mt)
#pragma unroll
        for (int nt = 0; nt < 4; ++nt)
          acc[mt][nt] = __builtin_amdgcn_mfma_f32_16x16x32_bf16(af[mt], bfr[nt], acc[mt][nt], 0, 0, 0);
    }
  }

  // epilogue — C/D layout: col = lane&15, row = (lane>>4)*4 + reg  [m89-verified]
  const int mode = p.mode;
  u16* Cz = p.C + (long)z * p.cz;
  float* Cfz = p.Cf + (long)z * p.cfz;
#pragma unroll
  for (int mt = 0; mt < 4; ++mt) {
#pragma unroll
    for (int nt = 0; nt < 4; ++nt) {
#pragma unroll
      for (int r = 0; r < 4; ++r) {
        long row = tileM + wm + mt * 16 + q * 4 + r;
        long col = tileN + wn + nt * 16 + r15;
        float v = acc[mt][nt][r];
        if (mode == MODE_PLAIN) {
          Cz[row * p.ldc + col] = f2bf(v);
        } else if (mode == MODE_QP) {
          long b = row >> 12, i = row & 4095;
          long addr = i * 1536 + b * 512 + col;
          p.C[addr] = f2bf(v);
          float s = (b == 0) ? 1.f : -0.5f;
          p.C2[addr] = f2bf(s * v);
        } else if (mode == MODE_SPLITN) {
          long b = col >> 12, i = col & 4095;
          p.C[b * 2097152 + row * 4096 + i] = f2bf(v);
        } else if (mode == MODE_ATOMIC) {
          unsafeAtomicAdd(&Cfz[row * 512 + col], v);   // global_atomic_add_f32
        } else {  // MODE_BIASF32
          p.Cf[row * 512 + col] = v + p.biasf[col];
        }
      }
    }
  }
}

// ---- small utility kernels ----

__global__ __launch_bounds__(256) void pack_m2_k(const float* wy, u16* M2) {
  int idx = blockIdx.x * 256 + threadIdx.x;   // 0..262143
  int i = idx >> 9, j = idx & 511;
  M2[(long)i * 1024 + j] = f2bf(wy[idx]);                  // [wy | wy^T]
  M2[(long)i * 1024 + 512 + j] = f2bf(wy[(long)j * 512 + i]);
}

__global__ __launch_bounds__(256) void init_ycat_k(const float* y, const float* feat, u16* Ycat) {
  long idx = (long)blockIdx.x * 256 + threadIdx.x;  // float4 units; 524288 total
  f32x4 a = ((const f32x4*)y)[idx];
  f32x4 f = ((const f32x4*)feat)[idx];
  u16x4 ua, uf;
#pragma unroll
  for (int i = 0; i < 4; ++i) { ua[i] = f2bf(a[i]); uf[i] = f2bf(f[i]); }
  ((u16x4*)Ycat)[idx] = ua;
  ((u16x4*)Ycat)[idx + 524288] = uf;
  ((u16x4*)Ycat)[idx + 1048576] = uf;
}

__global__ __launch_bounds__(256) void transpose_k(const u16* in, u16* out, long inz, long outz) {
  // in: [4096][512] bf16, out: [512][4096] bf16, 64x64 tiles
  __shared__ u16 t[64][68];
  const u16* src = in + (long)blockIdx.z * inz;
  u16* dst = out + (long)blockIdx.z * outz;
  int tid = threadIdx.x;
  int tr = tid >> 4, tc = (tid & 15) * 4;
  long r0 = (long)blockIdx.y * 64, c0 = (long)blockIdx.x * 64;
#pragma unroll
  for (int i = 0; i < 4; ++i) {
    int r = i * 16 + tr;
    uint2 v = *(const uint2*)(src + (r0 + r) * 512 + c0 + tc);
    t[r][tc] = (u16)(v.x & 0xffff); t[r][tc + 1] = (u16)(v.x >> 16);
    t[r][tc + 2] = (u16)(v.y & 0xffff); t[r][tc + 3] = (u16)(v.y >> 16);
  }
  __syncthreads();
#pragma unroll
  for (int i = 0; i < 4; ++i) {
    int r = i * 16 + tr;
    unsigned int a0 = t[tc + 0][r], a1 = t[tc + 1][r], a2 = t[tc + 2][r], a3 = t[tc + 3][r];
    uint2 v; v.x = a0 | (a1 << 16); v.y = a2 | (a3 << 16);
    *(uint2*)(dst + (c0 + r) * 4096 + r0 + tc) = v;
  }
}

// out[z] = E[z] + c1 * sigmoid(c2 * S[z])   (elementwise, [4096][512] per z)
__global__ __launch_bounds__(256) void reduce_epi_k(const float* S0, long sz, const float* E0, long ez,
                                                    u16* O0, long oz, float c1, float c2) {
  int z = blockIdx.y;
  long idx = (long)blockIdx.x * 256 + threadIdx.x;   // float4 units; 524288 per z
  f32x4 s = ((const f32x4*)(S0 + z * sz))[idx];
  f32x4 e = ((const f32x4*)(E0 + z * ez))[idx];
  u16x4 o;
#pragma unroll
  for (int i = 0; i < 4; ++i) {
    float sg = 1.f / (1.f + __expf(-(c2 * s[i])));
    o[i] = f2bf(e[i] + c1 * sg);
  }
  ((u16x4*)(O0 + z * oz))[idx] = o;
}

__device__ __forceinline__ float waveRedSum(float v) {
#pragma unroll
  for (int o = 32; o > 0; o >>= 1) v += __shfl_down(v, o, 64);
  return v;
}
__device__ __forceinline__ float waveRedMax(float v) {
#pragma unroll
  for (int o = 32; o > 0; o >>= 1) v = fmaxf(v, __shfl_down(v, o, 64));
  return v;
}

__global__ __launch_bounds__(256) void l2norm_k(const u16* Ycat, u16* pb) {
  __shared__ float red[4];
  int i = blockIdx.x, b = blockIdx.y, t = threadIdx.x;
  const u16* row = Ycat + ((long)b * 4096 + (long)i) * 512;
  unsigned int v = *(const unsigned int*)(row + 2 * t);
  float x0 = bf2f((u16)(v & 0xffff)), x1 = bf2f((u16)(v >> 16));
  float w = waveRedSum(x0 * x0 + x1 * x1);
  if ((t & 63) == 0) red[t >> 6] = w;
  __syncthreads();
  float tot = red[0] + red[1] + red[2] + red[3];
  float inv = 1.f / fmaxf(sqrtf(tot), 1e-12f);
  unsigned int o = (unsigned int)f2bf(x0 * inv) | ((unsigned int)f2bf(x1 * inv) << 16);
  *(unsigned int*)(pb + (long)i * 1536 + b * 512 + 2 * t) = o;
}

__global__ __launch_bounds__(256) void logsoftmax_k(const float* lg, float* out) {
  __shared__ float red[4];
  int i = blockIdx.x, t = threadIdx.x;
  const float* row = lg + (long)i * 512;
  float a = row[t], b2 = row[t + 256];
  float m = waveRedMax(fmaxf(a, b2));
  if ((t & 63) == 0) red[t >> 6] = m;
  __syncthreads();
  float M = fmaxf(fmaxf(red[0], red[1]), fmaxf(red[2], red[3]));
  __syncthreads();
  float w = waveRedSum(__expf(a - M) + __expf(b2 - M));
  if ((t & 63) == 0) red[t >> 6] = w;
  __syncthreads();
  float S = red[0] + red[1] + red[2] + red[3];
  float lse = M + __logf(S);
  out[(long)i * 512 + t] = a - lse;
  out[(long)i * 512 + t + 256] = b2 - lse;
}

extern "C" void kernel_launch(void* const* d_in, const int* in_sizes, int n_in,
                              void* d_out, int out_size, void* d_ws, size_t ws_size,
                              hipStream_t stream) {
  const float* feat = (const float*)d_in[0];
  const float* adj  = (const float*)d_in[1];
  const float* adj1 = (const float*)d_in[2];
  const float* y    = (const float*)d_in[3];
  const float* wy   = (const float*)d_in[4];
  const float* w2w  = (const float*)d_in[5];
  const float* w2b  = (const float*)d_in[6];
  (void)in_sizes; (void)n_in; (void)out_size; (void)ws_size;

  char* ws = (char*)d_ws;
  size_t off = 0;
  auto alloc = [&](size_t bytes) -> void* {
    void* r = ws + off; off += (bytes + 255) & ~(size_t)255; return r;
  };
  u16* M2   = (u16*)alloc(512L * 1024 * 2);
  u16* Wsum = (u16*)alloc(512L * 512 * 2);
  u16* Ycat = (u16*)alloc(3L * 4096 * 512 * 2);
  u16* Q    = (u16*)alloc(4096L * 1536 * 2);   // also Sy (8MB) + Sz[0] head
  u16* P    = (u16*)alloc(4096L * 1536 * 2);   // Sz tail (Q..P = 24MB exactly)
  float* Uf = (float*)alloc(2L * 4096 * 512 * 4);
  u16* Tt   = (u16*)alloc(3L * 512 * 4096 * 2);
  u16* Zt   = (u16*)alloc(2L * 512 * 4096 * 2);
  u16* t11  = (u16*)alloc(4096L * 4096 * 2);
  float* Sy = (float*)Q;                 // 4096*512 f32
  float* Sz = Sy + 2097152;              // 2 x 4096*512 f32 (spills into P region)
  u16* pb = Q;                           // final: Q/P dead
  float* logits = (float*)Zt;            // final: Zt dead
  const long S = 2097152;                // 4096*512

  pack_m2_k<<<1024, 256, 0, stream>>>(wy, M2);
  init_ycat_k<<<2048, 256, 0, stream>>>(y, feat, Ycat);

  { GemmP p = {}; p.A0 = p.A1 = M2; p.B = M2; p.lda = 1024; p.ldb = 1024; p.K = 1024;
    p.mode = MODE_PLAIN; p.C = Wsum; p.ldc = 512;
    gemm_nt<<<dim3(4, 4, 1), 256, 0, stream>>>(p); }           // Wsum = wy@wy^T + wy^T@wy

  for (int L = 0; L < 2; ++L) {
    { GemmP p = {}; p.A0 = p.A1 = Ycat; p.B = M2 + 512; p.lda = 512; p.ldb = 1024; p.K = 512;
      p.mode = MODE_QP; p.C = Q; p.C2 = P;
      gemm_nt<<<dim3(4, 96, 1), 256, 0, stream>>>(p); }        // Q=[yw|z1w|z2w], P scaled
    { GemmP p = {}; p.A0 = p.A1 = Wsum; p.B = Ycat; p.lda = 512; p.ldb = 512; p.K = 512;
      p.mode = MODE_SPLITN; p.C = Tt;
      gemm_nt<<<dim3(96, 4, 1), 256, 0, stream>>>(p); }        // Tt[b] = (Ycat[b]@Wsum)^T
    { GemmP p = {}; p.A0 = p.A1 = P; p.B = Q; p.lda = 1536; p.ldb = 1536; p.K = 1536;
      p.mode = MODE_PLAIN; p.C = t11; p.ldc = 4096;
      gemm_nt<<<dim3(32, 32, 1), 256, 0, stream>>>(p); }       // temp11 = P@Q^T
    transpose_k<<<dim3(8, 64, 2), 256, 0, stream>>>(Ycat + S, Zt, S, S);  // z1^T, z2^T

    // zero split-K accumulators: Sy(8MB) + Sz(16MB) + Uf(16MB) contiguous
    hipMemsetAsync(Sy, 0, (size_t)(8 + 16 + 16) * 1024 * 1024, stream);

    { GemmP p = {}; p.Af0 = adj; p.Af1 = adj1; p.B = Zt; p.bz = S; p.lda = 4096; p.ldb = 4096;
      p.K = 1024; p.ksl = 2; p.mode = MODE_ATOMIC; p.Cf = Uf; p.cfz = S;
      gemm_nt<<<dim3(4, 32, 8), 256, 0, stream>>>(p); }        // Uf[z] += adj_z @ z_z (split-K4)
    { GemmP p = {}; p.A0 = p.A1 = t11; p.B = Tt; p.lda = 4096; p.ldb = 4096;
      p.K = 512; p.ksl = 3; p.mode = MODE_ATOMIC; p.Cf = Sy; p.cfz = 0;
      gemm_nt<<<dim3(4, 32, 8), 256, 0, stream>>>(p); }        // Sy += t11 @ t12 (split-K8)
    { GemmP p = {}; p.A0 = p.A1 = t11; p.B = Tt + S; p.bz = S; p.lda = 4096; p.ldb = 4096;
      p.K = 1024; p.ksl = 2; p.mode = MODE_ATOMIC; p.Cf = Sz; p.cfz = S;
      gemm_nt<<<dim3(4, 32, 8), 256, 0, stream>>>(p); }        // Sz[z] += t11 @ t_z (split-K4)

    reduce_epi_k<<<dim3(2048, 1), 256, 0, stream>>>(Sy, 0, feat, 0, Ycat, 0, -0.5f, 1.f);
    reduce_epi_k<<<dim3(2048, 2), 256, 0, stream>>>(Sz, S, Uf, S, Ycat + S, S, -0.25f, -1.f);
  }

  l2norm_k<<<dim3(4096, 3, 1), 256, 0, stream>>>(Ycat, pb);
  { GemmP p = {}; p.A0 = p.A1 = pb; p.Bf = w2w; p.lda = 1536; p.ldb = 1536; p.K = 1536;
    p.mode = MODE_BIASF32; p.Cf = logits; p.biasf = w2b;
    gemm_nt<<<dim3(4, 32, 1), 256, 0, stream>>>(p); }          // logits = p@w2w^T + b
  logsoftmax_k<<<4096, 256, 0, stream>>>(logits, (float*)d_out);
}

// Round 4
// 650.206 us; speedup vs baseline: 1.6842x; 1.6842x over previous
//
#include <hip/hip_runtime.h>
#include <string.h>

typedef unsigned short u16;
typedef __bf16 bf16_t;
typedef bf16_t bf16x8 __attribute__((ext_vector_type(8)));
typedef float f32x4 __attribute__((ext_vector_type(4)));
typedef u16 u16x4 __attribute__((ext_vector_type(4)));

#define MODE_PLAIN 0
#define MODE_FUSEQT 1
#define MODE_PARTIAL 2
#define MODE_SFIN 3
#define MODE_BIASF32 4

#define SLC 2097152L   // 4096*512

__device__ __forceinline__ float bf2f(u16 u) {
  unsigned int x = ((unsigned int)u) << 16;
  return __builtin_bit_cast(float, x);
}
__device__ __forceinline__ u16 f2bf(float f) {
  unsigned int x = __builtin_bit_cast(unsigned int, f);
  x += 0x7fffu + ((x >> 16) & 1u);
  return (u16)(x >> 16);
}

__device__ __forceinline__ void gload_lds16(const void* g, void* l) {
  __builtin_amdgcn_global_load_lds(
      (const __attribute__((address_space(1))) void*)g,
      (__attribute__((address_space(3))) void*)l, 16, 0, 0);
}

struct GemmP {
  const u16* A0; const u16* A1;   // bf16 A, z-select (z = blockIdx.z >> ksl)
  const u16* B;  long bz;         // bf16 B
  const float* Bf;                // f32 B (logits) — overrides B
  int lda, ldb, K, ksl, mode;     // K = per-chunk K
  u16* C; int ldc;                // PLAIN
  u16* XwT; u16* TTp; u16* Pn;    // FUSEQT
  float* Cf; long cfz; int ldcf;  // PARTIAL: Cf[blockIdx.z*cfz + row*ldcf + col]
  const float* Ef; const float* Up; u16* Yc;   // SFIN
  const float* biasf; float* Cff; // BIASF32
};

// C[m][n] = sum_k A[m][k]*B[n][k]  (A:[M,K], B:[N,K]; M,N %128==0, K%64==0)
__global__ __launch_bounds__(256) void gemm_nt(GemmP p) {
  __shared__ u16 smem[2 * 128 * 64];   // A tile then B tile, 16B chunks, XOR swizzle
  const int tid = threadIdx.x;
  const int lane = tid & 63, wave = tid >> 6;
  const int z = blockIdx.z >> p.ksl;
  const int kc = blockIdx.z & ((1 << p.ksl) - 1);
  const long tileM = (long)blockIdx.y * 128;
  const long tileN = (long)blockIdx.x * 128;
  u16* ldsA = smem;
  u16* ldsB = smem + 128 * 64;

  const u16* A = (z == 0) ? p.A0 : p.A1;
  const u16* B = p.B + (long)z * p.bz;
  const float* Bf = p.Bf;

  // bf16 staging: issue j covers rows [j*32, j*32+32); lane l -> row j*32+wave*8+l/8
  const int srow = wave * 8 + (lane >> 3);
  const int ssc = lane & 7;
  long aoff[4], boff[4];
#pragma unroll
  for (int j = 0; j < 4; ++j) {
    int r = j * 32 + srow;
    int c = ssc ^ (r & 7);               // LDS[r][ssc] holds global chunk c
    aoff[j] = ((tileM + r) * (long)p.lda + c * 8) * 2;
    boff[j] = ((tileN + r) * (long)p.ldb + c * 8) * 2;
  }
  const int frow = tid >> 4, fcol = tid & 15;  // f32 staging coords

  const int r15 = lane & 15, q = lane >> 4;
  const int wm = (wave & 1) * 64, wn = (wave >> 1) * 64;

  f32x4 acc[4][4];
#pragma unroll
  for (int i = 0; i < 4; ++i)
#pragma unroll
    for (int j = 0; j < 4; ++j) { f32x4 zz = {0.f, 0.f, 0.f, 0.f}; acc[i][j] = zz; }

  const int K64 = p.K >> 6;                 // k-tiles per chunk
  const long kofs = (long)kc * K64;
  for (int kt = 0; kt < K64; ++kt) {
    const long kb = (kofs + kt) * 128;      // bf16 byte offset of this k-tile
    __syncthreads();
#pragma unroll
    for (int j = 0; j < 4; ++j)
      gload_lds16((const char*)A + aoff[j] + kb, (char*)ldsA + (j * 256 + wave * 64) * 16);
    if (Bf) {
#pragma unroll
      for (int i = 0; i < 8; ++i) {
        int r = i * 16 + frow;
        f32x4 v = *(const f32x4*)(Bf + (tileN + r) * (long)p.ldb + (kofs + kt) * 64 + fcol * 4);
        int sc = (fcol >> 1) ^ (r & 7);
        u16x4 o; o[0] = f2bf(v[0]); o[1] = f2bf(v[1]); o[2] = f2bf(v[2]); o[3] = f2bf(v[3]);
        *(u16x4*)(ldsB + (r * 8 + sc) * 8 + (fcol & 1) * 4) = o;
      }
    } else {
#pragma unroll
      for (int j = 0; j < 4; ++j)
        gload_lds16((const char*)B + boff[j] + kb, (char*)ldsB + (j * 256 + wave * 64) * 16);
    }
    __syncthreads();
#pragma unroll
    for (int ks = 0; ks < 2; ++ks) {
      bf16x8 af[4], bfr[4];
#pragma unroll
      for (int mt = 0; mt < 4; ++mt) {
        int row = wm + mt * 16 + r15;
        int sc = (ks * 4 + q) ^ (r15 & 7);
        af[mt] = *(const bf16x8*)(ldsA + (row * 8 + sc) * 8);
      }
#pragma unroll
      for (int nt = 0; nt < 4; ++nt) {
        int row = wn + nt * 16 + r15;
        int sc = (ks * 4 + q) ^ (r15 & 7);
        bfr[nt] = *(const bf16x8*)(ldsB + (row * 8 + sc) * 8);
      }
#pragma unroll
      for (int mt = 0; mt < 4; ++mt)
#pragma unroll
        for (int nt = 0; nt < 4; ++nt)
          acc[mt][nt] = __builtin_amdgcn_mfma_f32_16x16x32_bf16(af[mt], bfr[nt], acc[mt][nt], 0, 0, 0);
    }
  }

  // epilogue — C/D layout: col = lane&15, row = (lane>>4)*4 + reg  [m89-verified]
  const int mode = p.mode;
#pragma unroll
  for (int mt = 0; mt < 4; ++mt) {
#pragma unroll
    for (int nt = 0; nt < 4; ++nt) {
      long row0 = tileM + wm + mt * 16 + q * 4;   // 4 consecutive rows row0..row0+3
      long col = tileN + wn + nt * 16 + r15;
      if (mode == MODE_FUSEQT) {
        // row = bm*4096 + n; vectorized transposed stores (n contiguous over r)
        long bm = row0 >> 12, n0 = row0 & 4095;
        u16x4 ov;
#pragma unroll
        for (int r = 0; r < 4; ++r) ov[r] = f2bf(acc[mt][nt][r]);
        if (col < 512) {
          *(u16x4*)(p.XwT + (bm * 512 + col) * 4096 + n0) = ov;   // Q^T block
          float s = (bm == 0) ? 1.f : -0.5f;
          u16* pn = p.Pn + n0 * 1536 + bm * 512 + col;
#pragma unroll
          for (int r = 0; r < 4; ++r) pn[(long)r * 1536] = f2bf(s * acc[mt][nt][r]);
        } else {
          *(u16x4*)(p.TTp + (bm * 512 + (col - 512)) * 4096 + n0) = ov;  // T^T block
        }
      } else if (mode == MODE_PARTIAL) {
        float* c = p.Cf + (long)blockIdx.z * p.cfz + row0 * p.ldcf + col;
#pragma unroll
        for (int r = 0; r < 4; ++r) c[(long)r * p.ldcf] = acc[mt][nt][r];
      } else if (mode == MODE_SFIN) {
        long b = col >> 9, f = col & 511;
#pragma unroll
        for (int r = 0; r < 4; ++r) {
          long row = row0 + r;
          float v = acc[mt][nt][r];
          float o;
          if (b == 0) {
            o = p.Ef[row * 512 + f] - 0.5f * (1.f / (1.f + __expf(-v)));
          } else {
            const float* u = p.Up + (b - 1) * 2 * SLC + row * 512 + f;
            float e = u[0] + u[SLC];
            o = e - 0.25f * (1.f / (1.f + __expf(v)));   // sigmoid(-v)
          }
          p.Yc[b * SLC + row * 512 + f] = f2bf(o);
        }
      } else if (mode == MODE_BIASF32) {
#pragma unroll
        for (int r = 0; r < 4; ++r)
          p.Cff[(row0 + r) * 512 + col] = acc[mt][nt][r] + p.biasf[col];
      } else {  // MODE_PLAIN
#pragma unroll
        for (int r = 0; r < 4; ++r)
          p.C[(row0 + r) * (long)p.ldc + col] = f2bf(acc[mt][nt][r]);
      }
    }
  }
}

// ---- small utility kernels ----

__global__ __launch_bounds__(256) void pack_m2_k(const float* wy, u16* M2, u16* Bcat) {
  int idx = blockIdx.x * 256 + threadIdx.x;   // 0..262143
  int i = idx >> 9, j = idx & 511;
  u16 a = f2bf(wy[idx]);
  u16 b = f2bf(wy[(long)j * 512 + i]);
  M2[(long)i * 1024 + j] = a;          // [wy | wy^T]
  M2[(long)i * 1024 + 512 + j] = b;
  Bcat[(long)i * 512 + j] = b;         // rows 0..511 of Bcat = wy^T
}

__global__ __launch_bounds__(256) void init_ycat_k(const float* y, const float* feat, u16* Ycat) {
  long idx = (long)blockIdx.x * 256 + threadIdx.x;  // f32x4 units; 524288 total
  f32x4 a = ((const f32x4*)y)[idx];
  f32x4 f = ((const f32x4*)feat)[idx];
  u16x4 ua, uf;
#pragma unroll
  for (int i = 0; i < 4; ++i) { ua[i] = f2bf(a[i]); uf[i] = f2bf(f[i]); }
  ((u16x4*)Ycat)[idx] = ua;
  ((u16x4*)Ycat)[idx + 524288] = uf;
  ((u16x4*)Ycat)[idx + 1048576] = uf;
}

__global__ __launch_bounds__(256) void cvt_adj_k(const float* a0, const float* a1, u16* dst) {
  int z = blockIdx.y;
  const float* src = z ? a1 : a0;
  long idx = (long)blockIdx.x * 256 + threadIdx.x;  // f32x4 units; 4194304 per z
  f32x4 v = ((const f32x4*)src)[idx];
  u16x4 o;
#pragma unroll
  for (int i = 0; i < 4; ++i) o[i] = f2bf(v[i]);
  ((u16x4*)(dst + (long)z * 16777216))[idx] = o;
}

__global__ __launch_bounds__(256) void transpose_k(const u16* in, u16* out, long inz, long outz) {
  // in: [4096][512] bf16, out: [512][4096] bf16, 64x64 tiles
  __shared__ u16 t[64][68];
  const u16* src = in + (long)blockIdx.z * inz;
  u16* dst = out + (long)blockIdx.z * outz;
  int tid = threadIdx.x;
  int tr = tid >> 4, tc = (tid & 15) * 4;
  long r0 = (long)blockIdx.y * 64, c0 = (long)blockIdx.x * 64;
#pragma unroll
  for (int i = 0; i < 4; ++i) {
    int r = i * 16 + tr;
    uint2 v = *(const uint2*)(src + (r0 + r) * 512 + c0 + tc);
    t[r][tc] = (u16)(v.x & 0xffff); t[r][tc + 1] = (u16)(v.x >> 16);
    t[r][tc + 2] = (u16)(v.y & 0xffff); t[r][tc + 3] = (u16)(v.y >> 16);
  }
  __syncthreads();
#pragma unroll
  for (int i = 0; i < 4; ++i) {
    int r = i * 16 + tr;
    unsigned int a0 = t[tc + 0][r], a1 = t[tc + 1][r], a2 = t[tc + 2][r], a3 = t[tc + 3][r];
    uint2 v; v.x = a0 | (a1 << 16); v.y = a2 | (a3 << 16);
    *(uint2*)(dst + (c0 + r) * 4096 + r0 + tc) = v;
  }
}

__global__ __launch_bounds__(256) void wt_reduce_k(const float* Wp, u16* Wt) {
  long idx = (long)blockIdx.x * 256 + threadIdx.x;  // f32x4 units; 589824 total
  f32x4 s = ((const f32x4*)Wp)[idx];
#pragma unroll
  for (int kc = 1; kc < 4; ++kc) s += ((const f32x4*)Wp)[idx + (long)kc * 589824];
  u16x4 o;
#pragma unroll
  for (int i = 0; i < 4; ++i) o[i] = f2bf(s[i]);
  ((u16x4*)Wt)[idx] = o;
}

__device__ __forceinline__ float waveRedSum(float v) {
#pragma unroll
  for (int o = 32; o > 0; o >>= 1) v += __shfl_down(v, o, 64);
  return v;
}
__device__ __forceinline__ float waveRedMax(float v) {
#pragma unroll
  for (int o = 32; o > 0; o >>= 1) v = fmaxf(v, __shfl_down(v, o, 64));
  return v;
}

__global__ __launch_bounds__(256) void l2norm_k(const u16* Ycat, u16* pb) {
  __shared__ float red[4];
  int i = blockIdx.x, b = blockIdx.y, t = threadIdx.x;
  const u16* row = Ycat + ((long)b * 4096 + (long)i) * 512;
  unsigned int v = *(const unsigned int*)(row + 2 * t);
  float x0 = bf2f((u16)(v & 0xffff)), x1 = bf2f((u16)(v >> 16));
  float w = waveRedSum(x0 * x0 + x1 * x1);
  if ((t & 63) == 0) red[t >> 6] = w;
  __syncthreads();
  float tot = red[0] + red[1] + red[2] + red[3];
  float inv = 1.f / fmaxf(sqrtf(tot), 1e-12f);
  unsigned int o = (unsigned int)f2bf(x0 * inv) | ((unsigned int)f2bf(x1 * inv) << 16);
  *(unsigned int*)(pb + (long)i * 1536 + b * 512 + 2 * t) = o;
}

__global__ __launch_bounds__(256) void logsoftmax_k(const float* lg, float* out) {
  __shared__ float red[4];
  int i = blockIdx.x, t = threadIdx.x;
  const float* row = lg + (long)i * 512;
  float a = row[t], b2 = row[t + 256];
  float m = waveRedMax(fmaxf(a, b2));
  if ((t & 63) == 0) red[t >> 6] = m;
  __syncthreads();
  float M = fmaxf(fmaxf(red[0], red[1]), fmaxf(red[2], red[3]));
  __syncthreads();
  float w = waveRedSum(__expf(a - M) + __expf(b2 - M));
  if ((t & 63) == 0) red[t >> 6] = w;
  __syncthreads();
  float S = red[0] + red[1] + red[2] + red[3];
  float lse = M + __logf(S);
  out[(long)i * 512 + t] = a - lse;
  out[(long)i * 512 + t + 256] = b2 - lse;
}

extern "C" void kernel_launch(void* const* d_in, const int* in_sizes, int n_in,
                              void* d_out, int out_size, void* d_ws, size_t ws_size,
                              hipStream_t stream) {
  const float* feat = (const float*)d_in[0];
  const float* adj  = (const float*)d_in[1];
  const float* adj1 = (const float*)d_in[2];
  const float* y    = (const float*)d_in[3];
  const float* wy   = (const float*)d_in[4];
  const float* w2w  = (const float*)d_in[5];
  const float* w2b  = (const float*)d_in[6];
  (void)in_sizes; (void)n_in; (void)out_size; (void)ws_size;

  char* ws = (char*)d_ws;
  size_t off = 0;
  auto alloc = [&](size_t bytes) -> void* {
    void* r = ws + off; off += (bytes + 255) & ~(size_t)255; return r;
  };
  u16* M2   = (u16*)alloc(512L * 1024 * 2);        // [wy | wy^T]
  u16* Bcat = (u16*)alloc(1024L * 512 * 2);        // [wy^T rows | Wsum rows]
  u16* adjb = (u16*)alloc(2L * 4096 * 4096 * 2);   // bf16 adj, adj1
  u16* Ycat = (u16*)alloc(3L * 4096 * 512 * 2);    // y,z1,z2 node-major
  u16* Pn   = (u16*)alloc(4096L * 1536 * 2);       // P node-major (scaled)
  u16* XwT  = (u16*)alloc(3L * 512 * 4096 * 2);    // (Ycat@wy)^T per block; later pb
  u16* TT   = (u16*)alloc(3L * 512 * 4096 * 2);    // (Ycat@Wsum)^T per block
  u16* Zt   = (u16*)alloc(2L * 512 * 4096 * 2);    // z1^T,z2^T; later logits f32
  u16* Wt   = (u16*)alloc(1536L * 1536 * 2);       // W^T bf16
  float* WU = (float*)alloc(4L * 1536 * 1536 * 4); // Wp partials / Up partials (disjoint lifetimes)
  u16* pb = XwT;
  float* logits = (float*)Zt;

  pack_m2_k<<<1024, 256, 0, stream>>>(wy, M2, Bcat);
  init_ycat_k<<<2048, 256, 0, stream>>>(y, feat, Ycat);
  cvt_adj_k<<<dim3(16384, 2), 256, 0, stream>>>(adj, adj1, adjb);

  { GemmP p = {}; p.A0 = p.A1 = M2; p.B = M2; p.lda = 1024; p.ldb = 1024; p.K = 1024;
    p.mode = MODE_PLAIN; p.C = Bcat + 512L * 512; p.ldc = 512;
    gemm_nt<<<dim3(4, 4, 1), 256, 0, stream>>>(p); }   // Bcat rows 512..1023 = Wsum

  for (int L = 0; L < 2; ++L) {
    // Fused: Xw = Ycat@wy (-> XwT transposed + Pn scaled) and T = Ycat@Wsum (-> TT)
    { GemmP p = {}; p.A0 = p.A1 = Ycat; p.B = Bcat; p.lda = 512; p.ldb = 512; p.K = 512;
      p.mode = MODE_FUSEQT; p.XwT = XwT; p.TTp = TT; p.Pn = Pn;
      gemm_nt<<<dim3(8, 96, 1), 256, 0, stream>>>(p); }
    transpose_k<<<dim3(8, 64, 2), 256, 0, stream>>>(Ycat + SLC, Zt, SLC, SLC);  // z1^T,z2^T
    // Wt[j,i] = sum_n TT[j,n]*XwT[i,n]  (= W^T), split-K4 into f32 partials
    { GemmP p = {}; p.A0 = p.A1 = TT; p.B = XwT; p.lda = 4096; p.ldb = 4096;
      p.K = 1024; p.ksl = 2; p.mode = MODE_PARTIAL; p.Cf = WU; p.cfz = 2359296; p.ldcf = 1536;
      gemm_nt<<<dim3(12, 12, 4), 256, 0, stream>>>(p); }
    wt_reduce_k<<<2304, 256, 0, stream>>>(WU, Wt);
    // U[z] = adj_z @ z_z, split-K2 into f32 partials (summed in S epilogue)
    { GemmP p = {}; p.A0 = adjb; p.A1 = adjb + 16777216L; p.B = Zt; p.bz = SLC;
      p.lda = 4096; p.ldb = 4096; p.K = 2048; p.ksl = 1;
      p.mode = MODE_PARTIAL; p.Cf = WU; p.cfz = SLC; p.ldcf = 512;
      gemm_nt<<<dim3(4, 32, 4), 256, 0, stream>>>(p); }
    // S = Pn @ Wt^T; epilogue applies all three sigmoid updates into Ycat
    { GemmP p = {}; p.A0 = p.A1 = Pn; p.B = Wt; p.lda = 1536; p.ldb = 1536; p.K = 1536;
      p.mode = MODE_SFIN; p.Ef = feat; p.Up = WU; p.Yc = Ycat;
      gemm_nt<<<dim3(12, 32, 1), 256, 0, stream>>>(p); }
  }

  l2norm_k<<<dim3(4096, 3, 1), 256, 0, stream>>>(Ycat, pb);
  { GemmP p = {}; p.A0 = p.A1 = pb; p.Bf = w2w; p.lda = 1536; p.ldb = 1536; p.K = 1536;
    p.mode = MODE_BIASF32; p.Cff = logits; p.biasf = w2b;
    gemm_nt<<<dim3(4, 32, 1), 256, 0, stream>>>(p); }
  logsoftmax_k<<<4096, 256, 0, stream>>>(logits, (float*)d_out);
}

// Round 5
// 637.291 us; speedup vs baseline: 1.7183x; 1.0203x over previous
//
#include <hip/hip_runtime.h>

typedef unsigned short u16;
typedef __bf16 bf16_t;
typedef bf16_t bf16x8 __attribute__((ext_vector_type(8)));
typedef float f32x4 __attribute__((ext_vector_type(4)));
typedef u16 u16x4 __attribute__((ext_vector_type(4)));

#define MODE_PLAIN 0
#define MODE_FUSEQT 1
#define MODE_PARTIAL 2
#define MODE_SFIN 3
#define MODE_CVT 4
#define MODE_INIT 5
#define MODE_TRANS 6

#define SLC 2097152L   // 4096*512

__device__ __forceinline__ float bf2f(u16 u) {
  unsigned int x = ((unsigned int)u) << 16;
  return __builtin_bit_cast(float, x);
}
__device__ __forceinline__ u16 f2bf(float f) {
  unsigned int x = __builtin_bit_cast(unsigned int, f);
  x += 0x7fffu + ((x >> 16) & 1u);
  return (u16)(x >> 16);
}

__device__ __forceinline__ void gload_lds16(const void* g, void* l) {
  __builtin_amdgcn_global_load_lds(
      (const __attribute__((address_space(1))) void*)g,
      (__attribute__((address_space(3))) void*)l, 16, 0, 0);
}

struct Job {
  int mode, gx, gy, ksl;          // gemm grid (x-major-outer decode), log2 K-chunks
  const u16 *A0, *A1, *B; long bz;
  const float *Bf;                // f32 B (logits) — overrides B
  int lda, ldb, K;                // K = per-chunk K
  u16 *C; long cfz; int ldc;      // PLAIN dst / TRANS dst(+z-stride)
  u16 *XwT, *TTp, *Pn;            // FUSEQT
  float *Cf; int ldcf;            // PARTIAL: Cf[zi*cfz + row*ldcf + col]
  const float *Ef, *Up; u16 *Yc;  // SFIN
  const float *S0, *S1; u16 *D0;  // CVT / INIT
};
struct LaunchP { Job j[3]; int s1, s2; };

__device__ __forceinline__ void run_job(const Job& p, int rb, u16* smem) {
  const int tid = threadIdx.x;

  if (p.mode == MODE_CVT) {       // adj/adj1 f32 -> adjb bf16 (512 blocks)
    const float* src = (rb < 256) ? p.S0 : p.S1;
    u16* dst = p.D0 + ((rb < 256) ? 0L : 16777216L);
    int r = rb & 255;
#pragma unroll 4
    for (int i = 0; i < 64; ++i) {
      long idx = (long)i * 65536 + r * 256 + tid;
      f32x4 v = ((const f32x4*)src)[idx];
      u16x4 o;
#pragma unroll
      for (int k = 0; k < 4; ++k) o[k] = f2bf(v[k]);
      ((u16x4*)dst)[idx] = o;
    }
    return;
  }
  if (p.mode == MODE_INIT) {      // y,feat f32 -> Ycat bf16 x3 (256 blocks)
#pragma unroll
    for (int i = 0; i < 8; ++i) {
      long idx = (long)i * 65536 + rb * 256 + tid;
      f32x4 a = ((const f32x4*)p.S0)[idx];
      f32x4 f = ((const f32x4*)p.S1)[idx];
      u16x4 ua, uf;
#pragma unroll
      for (int k = 0; k < 4; ++k) { ua[k] = f2bf(a[k]); uf[k] = f2bf(f[k]); }
      ((u16x4*)p.D0)[idx] = ua;
      ((u16x4*)p.D0)[idx + 524288] = uf;
      ((u16x4*)p.D0)[idx + 1048576] = uf;
    }
    return;
  }
  if (p.mode == MODE_TRANS) {     // [4096,512] -> [512,4096], 64x64 tiles, z in {0,1}
    u16 (*t)[68] = (u16(*)[68])smem;
    int zi = rb >> 9, rem = rb & 511;
    int bx = rem >> 6, by = rem & 63;
    const u16* src = p.A0 + (long)zi * p.bz;
    u16* dst = p.C + (long)zi * p.cfz;
    int tr = tid >> 4, tc = (tid & 15) * 4;
    long r0 = (long)by * 64, c0 = (long)bx * 64;
#pragma unroll
    for (int i = 0; i < 4; ++i) {
      int r = i * 16 + tr;
      uint2 v = *(const uint2*)(src + (r0 + r) * 512 + c0 + tc);
      t[r][tc] = (u16)(v.x & 0xffff); t[r][tc + 1] = (u16)(v.x >> 16);
      t[r][tc + 2] = (u16)(v.y & 0xffff); t[r][tc + 3] = (u16)(v.y >> 16);
    }
    __syncthreads();
#pragma unroll
    for (int i = 0; i < 4; ++i) {
      int r = i * 16 + tr;
      unsigned int a0 = t[tc + 0][r], a1 = t[tc + 1][r], a2 = t[tc + 2][r], a3 = t[tc + 3][r];
      uint2 v; v.x = a0 | (a1 << 16); v.y = a2 | (a3 << 16);
      *(uint2*)(dst + (c0 + r) * 4096 + r0 + tc) = v;
    }
    return;
  }

  // ---- gemm: C[m][n] = sum_k A[m][k]*B[n][k] ----
  const int lane = tid & 63, wave = tid >> 6;
  int per = p.gx * p.gy;
  int zi = rb / per, rem = rb - zi * per;
  int bx = rem / p.gy, by = rem - bx * p.gy;   // x-major-outer: same-tileM blocks gy apart
  int z = zi >> p.ksl, kc = zi & ((1 << p.ksl) - 1);
  const long tileM = (long)by * 128;
  const long tileN = (long)bx * 128;
  u16* ldsA = smem;
  u16* ldsB = smem + 128 * 64;

  const u16* A = (z == 0) ? p.A0 : p.A1;
  const u16* B = p.B + (long)z * p.bz;
  const float* Bf = p.Bf;

  const int srow = wave * 8 + (lane >> 3);
  const int ssc = lane & 7;
  long aoff[4], boff[4];
#pragma unroll
  for (int j = 0; j < 4; ++j) {
    int r = j * 32 + srow;
    int c = ssc ^ (r & 7);               // XOR swizzle: LDS[r][ssc] holds global chunk c
    aoff[j] = ((tileM + r) * (long)p.lda + c * 8) * 2;
    boff[j] = ((tileN + r) * (long)p.ldb + c * 8) * 2;
  }
  const int frow = tid >> 4, fcol = tid & 15;  // f32 staging coords

  const int r15 = lane & 15, q = lane >> 4;
  const int wm = (wave & 1) * 64, wn = (wave >> 1) * 64;

  f32x4 acc[4][4];
#pragma unroll
  for (int i = 0; i < 4; ++i)
#pragma unroll
    for (int j = 0; j < 4; ++j) { f32x4 zz = {0.f, 0.f, 0.f, 0.f}; acc[i][j] = zz; }

  const int K64 = p.K >> 6;
  const long kofs = (long)kc * K64;
  for (int kt = 0; kt < K64; ++kt) {
    const long kb = (kofs + kt) * 128;
    __syncthreads();
#pragma unroll
    for (int j = 0; j < 4; ++j)
      gload_lds16((const char*)A + aoff[j] + kb, (char*)ldsA + (j * 256 + wave * 64) * 16);
    if (Bf) {
#pragma unroll
      for (int i = 0; i < 8; ++i) {
        int r = i * 16 + frow;
        f32x4 v = *(const f32x4*)(Bf + (tileN + r) * (long)p.ldb + (kofs + kt) * 64 + fcol * 4);
        int sc = (fcol >> 1) ^ (r & 7);
        u16x4 o; o[0] = f2bf(v[0]); o[1] = f2bf(v[1]); o[2] = f2bf(v[2]); o[3] = f2bf(v[3]);
        *(u16x4*)(ldsB + (r * 8 + sc) * 8 + (fcol & 1) * 4) = o;
      }
    } else {
#pragma unroll
      for (int j = 0; j < 4; ++j)
        gload_lds16((const char*)B + boff[j] + kb, (char*)ldsB + (j * 256 + wave * 64) * 16);
    }
    __syncthreads();
#pragma unroll
    for (int ks = 0; ks < 2; ++ks) {
      bf16x8 af[4], bfr[4];
#pragma unroll
      for (int mt = 0; mt < 4; ++mt) {
        int row = wm + mt * 16 + r15;
        int sc = (ks * 4 + q) ^ (r15 & 7);
        af[mt] = *(const bf16x8*)(ldsA + (row * 8 + sc) * 8);
      }
#pragma unroll
      for (int nt = 0; nt < 4; ++nt) {
        int row = wn + nt * 16 + r15;
        int sc = (ks * 4 + q) ^ (r15 & 7);
        bfr[nt] = *(const bf16x8*)(ldsB + (row * 8 + sc) * 8);
      }
#pragma unroll
      for (int mt = 0; mt < 4; ++mt)
#pragma unroll
        for (int nt = 0; nt < 4; ++nt)
          acc[mt][nt] = __builtin_amdgcn_mfma_f32_16x16x32_bf16(af[mt], bfr[nt], acc[mt][nt], 0, 0, 0);
    }
  }

  // epilogue — C/D layout: col = lane&15, row = (lane>>4)*4 + reg  [m89-verified]
  const int mode = p.mode;
#pragma unroll
  for (int mt = 0; mt < 4; ++mt) {
#pragma unroll
    for (int nt = 0; nt < 4; ++nt) {
      long row0 = tileM + wm + mt * 16 + q * 4;
      long col = tileN + wn + nt * 16 + r15;
      if (mode == MODE_FUSEQT) {
        long bm = row0 >> 12, n0 = row0 & 4095;
        u16x4 ov;
#pragma unroll
        for (int r = 0; r < 4; ++r) ov[r] = f2bf(acc[mt][nt][r]);
        if (col < 512) {
          *(u16x4*)(p.XwT + (bm * 512 + col) * 4096 + n0) = ov;   // Q^T block
          float s = (bm == 0) ? 1.f : -0.5f;
          u16* pn = p.Pn + n0 * 1536 + bm * 512 + col;
#pragma unroll
          for (int r = 0; r < 4; ++r) pn[(long)r * 1536] = f2bf(s * acc[mt][nt][r]);
        } else {
          *(u16x4*)(p.TTp + (bm * 512 + (col - 512)) * 4096 + n0) = ov;  // T^T block
        }
      } else if (mode == MODE_PARTIAL) {
        float* c = p.Cf + (long)zi * p.cfz + row0 * p.ldcf + col;
#pragma unroll
        for (int r = 0; r < 4; ++r) c[(long)r * p.ldcf] = acc[mt][nt][r];
      } else if (mode == MODE_SFIN) {
        long b = col >> 9, f = col & 511;
#pragma unroll
        for (int r = 0; r < 4; ++r) {
          long row = row0 + r;
          float v = acc[mt][nt][r];
          float o;
          if (b == 0) {
            o = p.Ef[row * 512 + f] - 0.5f * (1.f / (1.f + __expf(-v)));
          } else {
            const float* u = p.Up + (b - 1) * 2 * SLC + row * 512 + f;
            float e = u[0] + u[SLC];
            o = e - 0.25f * (1.f / (1.f + __expf(v)));   // sigmoid(-v)
          }
          p.Yc[b * SLC + row * 512 + f] = f2bf(o);
        }
      } else {  // MODE_PLAIN
#pragma unroll
        for (int r = 0; r < 4; ++r)
          p.C[(row0 + r) * (long)p.ldc + col] = f2bf(acc[mt][nt][r]);
      }
    }
  }
}

__global__ __launch_bounds__(256) void fused_k(LaunchP lp) {
  __shared__ u16 smem[2 * 128 * 64];
  int bid = blockIdx.x;
  if (bid < lp.s1) run_job(lp.j[0], bid, smem);
  else if (bid < lp.s2) run_job(lp.j[1], bid - lp.s1, smem);
  else run_job(lp.j[2], bid - lp.s2, smem);
}

// ---- small standalone kernels ----

__global__ __launch_bounds__(256) void pack_m2_k(const float* wy, u16* M2, u16* Bcat) {
  int idx = blockIdx.x * 256 + threadIdx.x;   // 0..262143
  int i = idx >> 9, j = idx & 511;
  u16 a = f2bf(wy[idx]);
  u16 b = f2bf(wy[(long)j * 512 + i]);
  M2[(long)i * 1024 + j] = a;          // [wy | wy^T]
  M2[(long)i * 1024 + 512 + j] = b;
  Bcat[(long)i * 512 + j] = b;         // rows 0..511 of Bcat = wy^T
}

__device__ __forceinline__ float waveRedSum(float v) {
#pragma unroll
  for (int o = 32; o > 0; o >>= 1) v += __shfl_down(v, o, 64);
  return v;
}
__device__ __forceinline__ float waveRedMax(float v) {
#pragma unroll
  for (int o = 32; o > 0; o >>= 1) v = fmaxf(v, __shfl_down(v, o, 64));
  return v;
}

__global__ __launch_bounds__(256) void l2norm_k(const u16* Ycat, u16* pb) {
  __shared__ float red[4];
  int i = blockIdx.x, b = blockIdx.y, t = threadIdx.x;
  const u16* row = Ycat + ((long)b * 4096 + (long)i) * 512;
  unsigned int v = *(const unsigned int*)(row + 2 * t);
  float x0 = bf2f((u16)(v & 0xffff)), x1 = bf2f((u16)(v >> 16));
  float w = waveRedSum(x0 * x0 + x1 * x1);
  if ((t & 63) == 0) red[t >> 6] = w;
  __syncthreads();
  float tot = red[0] + red[1] + red[2] + red[3];
  float inv = 1.f / fmaxf(sqrtf(tot), 1e-12f);
  unsigned int o = (unsigned int)f2bf(x0 * inv) | ((unsigned int)f2bf(x1 * inv) << 16);
  *(unsigned int*)(pb + (long)i * 1536 + b * 512 + 2 * t) = o;
}

// sums 4 split-K logit partials + bias, then log_softmax
__global__ __launch_bounds__(256) void logsoftmax_k(const float* lg, const float* bias, float* out) {
  __shared__ float red[4];
  int i = blockIdx.x, t = threadIdx.x;
  const float* row = lg + (long)i * 512;
  float a  = row[t]       + row[t + SLC]       + row[t + 2 * SLC]       + row[t + 3 * SLC]       + bias[t];
  float b2 = row[t + 256] + row[t + 256 + SLC] + row[t + 256 + 2 * SLC] + row[t + 256 + 3 * SLC] + bias[t + 256];
  float m = waveRedMax(fmaxf(a, b2));
  if ((t & 63) == 0) red[t >> 6] = m;
  __syncthreads();
  float M = fmaxf(fmaxf(red[0], red[1]), fmaxf(red[2], red[3]));
  __syncthreads();
  float w = waveRedSum(__expf(a - M) + __expf(b2 - M));
  if ((t & 63) == 0) red[t >> 6] = w;
  __syncthreads();
  float S = red[0] + red[1] + red[2] + red[3];
  float lse = M + __logf(S);
  out[(long)i * 512 + t] = a - lse;
  out[(long)i * 512 + t + 256] = b2 - lse;
}

extern "C" void kernel_launch(void* const* d_in, const int* in_sizes, int n_in,
                              void* d_out, int out_size, void* d_ws, size_t ws_size,
                              hipStream_t stream) {
  const float* feat = (const float*)d_in[0];
  const float* adj  = (const float*)d_in[1];
  const float* adj1 = (const float*)d_in[2];
  const float* y    = (const float*)d_in[3];
  const float* wy   = (const float*)d_in[4];
  const float* w2w  = (const float*)d_in[5];
  const float* w2b  = (const float*)d_in[6];
  (void)in_sizes; (void)n_in; (void)out_size; (void)ws_size;

  char* ws = (char*)d_ws;
  size_t off = 0;
  auto alloc = [&](size_t bytes) -> void* {
    void* r = ws + off; off += (bytes + 255) & ~(size_t)255; return r;
  };
  u16* M2   = (u16*)alloc(512L * 1024 * 2);        // [wy | wy^T]
  u16* Bcat = (u16*)alloc(1024L * 512 * 2);        // [wy^T rows | Wsum rows]
  u16* adjb = (u16*)alloc(2L * 4096 * 4096 * 2);   // bf16 adj, adj1
  u16* Ycat = (u16*)alloc(3L * 4096 * 512 * 2);    // y,z1,z2 node-major
  u16* Pn   = (u16*)alloc(4096L * 1536 * 2);       // P node-major (scaled)
  u16* XwT  = (u16*)alloc(3L * 512 * 4096 * 2);    // (Ycat@wy)^T; later pb
  u16* TT   = (u16*)alloc(3L * 512 * 4096 * 2);    // (Ycat@Wsum)^T
  u16* Zt   = (u16*)alloc(2L * 512 * 4096 * 2);    // z1^T,z2^T
  u16* Wt   = (u16*)alloc(1536L * 1536 * 2);       // W^T bf16
  float* WU = (float*)alloc(4L * SLC * 4);         // U partials / logit partials
  u16* pb = XwT;

  pack_m2_k<<<1024, 256, 0, stream>>>(wy, M2, Bcat);

  { LaunchP lp = {};   // Wsum gemm (16) || INIT (256)
    Job& a = lp.j[0]; a.mode = MODE_PLAIN; a.gx = 4; a.gy = 4; a.K = 1024;
    a.A0 = a.A1 = M2; a.B = M2; a.lda = 1024; a.ldb = 1024;
    a.C = Bcat + 512L * 512; a.ldc = 512;
    Job& b = lp.j[1]; b.mode = MODE_INIT; b.S0 = y; b.S1 = feat; b.D0 = Ycat;
    lp.s1 = 16; lp.s2 = 272;
    fused_k<<<272, 256, 0, stream>>>(lp); }

  for (int L = 0; L < 2; ++L) {
    { LaunchP lp = {};   // FUSEQT (768) || TRANS (1024) || CVT (512, L0 only)
      Job& a = lp.j[0]; a.mode = MODE_FUSEQT; a.gx = 8; a.gy = 96; a.K = 512;
      a.A0 = a.A1 = Ycat; a.B = Bcat; a.lda = 512; a.ldb = 512;
      a.XwT = XwT; a.TTp = TT; a.Pn = Pn;
      Job& b = lp.j[1]; b.mode = MODE_TRANS; b.A0 = Ycat + SLC; b.bz = SLC;
      b.C = Zt; b.cfz = SLC;
      int grid = 1792;
      lp.s1 = 768; lp.s2 = 1792;
      if (L == 0) {
        Job& c = lp.j[2]; c.mode = MODE_CVT; c.S0 = adj; c.S1 = adj1; c.D0 = adjb;
        grid = 2304;
      }
      fused_k<<<grid, 256, 0, stream>>>(lp); }

    { LaunchP lp = {};   // U partials (512, split-K2) || Wt (144, K=4096)
      Job& a = lp.j[0]; a.mode = MODE_PARTIAL; a.gx = 4; a.gy = 32; a.ksl = 1; a.K = 2048;
      a.A0 = adjb; a.A1 = adjb + 16777216L; a.B = Zt; a.bz = SLC;
      a.lda = 4096; a.ldb = 4096; a.Cf = WU; a.cfz = SLC; a.ldcf = 512;
      Job& b = lp.j[1]; b.mode = MODE_PLAIN; b.gx = 12; b.gy = 12; b.K = 4096;
      b.A0 = b.A1 = TT; b.B = XwT; b.lda = 4096; b.ldb = 4096;
      b.C = Wt; b.ldc = 1536;
      lp.s1 = 512; lp.s2 = 656;
      fused_k<<<656, 256, 0, stream>>>(lp); }

    { LaunchP lp = {};   // SFIN: S = Pn @ Wt^T, fused sigmoid updates into Ycat
      Job& a = lp.j[0]; a.mode = MODE_SFIN; a.gx = 12; a.gy = 32; a.K = 1536;
      a.A0 = a.A1 = Pn; a.B = Wt; a.lda = 1536; a.ldb = 1536;
      a.Ef = feat; a.Up = WU; a.Yc = Ycat;
      lp.s1 = 384; lp.s2 = 384;
      fused_k<<<384, 256, 0, stream>>>(lp); }
  }

  l2norm_k<<<dim3(4096, 3, 1), 256, 0, stream>>>(Ycat, pb);

  { LaunchP lp = {};   // logits split-K4 partials (512 blocks)
    Job& a = lp.j[0]; a.mode = MODE_PARTIAL; a.gx = 4; a.gy = 32; a.ksl = 2; a.K = 384;
    a.A0 = a.A1 = pb; a.Bf = w2w; a.lda = 1536; a.ldb = 1536;
    a.Cf = WU; a.cfz = SLC; a.ldcf = 512;
    lp.s1 = 512; lp.s2 = 512;
    fused_k<<<512, 256, 0, stream>>>(lp); }

  logsoftmax_k<<<4096, 256, 0, stream>>>(WU, w2b, (float*)d_out);
}